// Round 22
// baseline (350.991 us; speedup 1.0000x reference)
//
#include <hip/hip_runtime.h>
#include <stdint.h>

typedef __attribute__((ext_vector_type(8))) _Float16 half8;
typedef __attribute__((ext_vector_type(4))) float f32x4;

#define CDIM 256
#define KCODES 1024
#define NPTS 131072
#define ZQ_ELEMS 33554432u
#define CAP 32768
#define MARGIN 3.0e-4f

// ws layout (bytes) — cbT (1MB) aliases WS_IMG region AFTER vq_dist (img dead by then)
#define WS_IMG 0
#define WS_S2 (16 * 65536)
#define WS_IDX (WS_S2 + 4096)
#define WS_PART (WS_IDX + NPTS * 4)
#define WS_CNT (WS_PART + 65536)
#define WS_LIST (WS_CNT + 64)

__device__ __forceinline__ float np_pairwise_sq_256(const float* x) {
    float res[2];
#pragma unroll
    for (int h = 0; h < 2; h++) {
        const float* a = x + h * 128;
        float r[8];
#pragma unroll
        for (int j = 0; j < 8; j++) r[j] = __fmul_rn(a[j], a[j]);
#pragma unroll
        for (int i = 8; i < 128; i += 8)
#pragma unroll
            for (int j = 0; j < 8; j++)
                r[j] = __fadd_rn(r[j], __fmul_rn(a[i + j], a[i + j]));
        res[h] = __fadd_rn(__fadd_rn(__fadd_rn(r[0], r[1]), __fadd_rn(r[2], r[3])),
                           __fadd_rn(__fadd_rn(r[4], r[5]), __fadd_rn(r[6], r[7])));
    }
    return __fadd_rn(res[0], res[1]);
}

// ---------------- fused prep: img fragments + s2 (32 codes/block, 32 blocks) --------
__global__ __launch_bounds__(256) void vq_prepall(const float* __restrict__ cb,
                                                  unsigned char* __restrict__ img,
                                                  float* __restrict__ s2,
                                                  int* __restrict__ cnt) {
    __shared__ float rows[32 * 261];
    int t = threadIdx.x;
    int k0 = blockIdx.x * 32;
    if (blockIdx.x == 0 && t == 0) *cnt = 0;
#pragma unroll
    for (int i = 0; i < 8; i++) {
        int u = i * 256 + t;
        int row = u >> 6, c4 = u & 63;
        float4 v = *(const float4*)&cb[(size_t)(k0 + row) * CDIM + c4 * 4];
        float* d = &rows[row * 261 + c4 * 4];
        d[0] = v.x; d[1] = v.y; d[2] = v.z; d[3] = v.w;
    }
    __syncthreads();
    if (t < 32) s2[k0 + t] = np_pairwise_sq_256(&rows[t * 261]);
#pragma unroll
    for (int i = 0; i < 4; i++) {
        int u = i * 256 + t;
        int cl = u >> 5, cg = u & 31;
        union H { _Float16 h[8]; uint4 u4; } hv;
#pragma unroll
        for (int j = 0; j < 8; j++) hv.h[j] = (_Float16)(rows[cl * 261 + cg * 8 + j] * 1024.f);
        int ks = cg >> 2, l4 = cg & 3;
        int q = cl >> 4, l15 = cl & 15;
        int lane = l4 * 16 + l15;
        *(uint4*)(img + (size_t)blockIdx.x * 16384 + ((ks * 2 + q) << 10) + lane * 16) = hv.u4;
    }
}

// ---------------- pass 1: high-TLP L2-direct B; M_rep=2; zero K-loop barriers -------------
// 1024 blocks x 256 thr (4 waves, 128 pts). LDS 20.5KB; __launch_bounds__(256,4) -> 4 blk/CU
// = 16 waves/CU: TLP hides the ~200cyc L2 latency of direct B loads (512KB image, L2-hot).
__global__ __launch_bounds__(256, 4) void vq_dist(const float* __restrict__ z,
                                                  const unsigned char* __restrict__ img,
                                                  const float* __restrict__ s2g,
                                                  int* __restrict__ outIdx,
                                                  int* __restrict__ cnt,
                                                  int* __restrict__ list,
                                                  float* __restrict__ partial) {
    __shared__ __align__(16) unsigned char az[16384];
    __shared__ float e2s[1024];
    __shared__ float lred[4];
    int t = threadIdx.x;
    int lane = t & 63, wave = t >> 6;
    int l15 = lane & 15, l4 = lane >> 4;
    int blk0 = blockIdx.x * 128;
    int wbase = blk0 + wave * 32;
    int b = blk0 >> 12;
    int hwb0 = blk0 & 4095;
    const float* zb = z + (size_t)b * (CDIM * 4096);

#pragma unroll
    for (int i = 0; i < 4; i++) e2s[t + i * 256] = s2g[t + i * 256];

    // prologue: 8 slices of [32ch x 128hw] = 16KB each; fp16 A-frags + exact S1
    half8 aHi[2][8];
    float s1p[2] = {0.f, 0.f};
#pragma unroll
    for (int ks = 0; ks < 8; ks++) {
        __syncthreads();
#pragma unroll
        for (int i = 0; i < 4; i++) {
            int u = i * 256 + t;               // 1024 units of 16B
            int row = u >> 5, col4 = u & 31;   // 128 floats/row
            const float* gsrc = zb + (size_t)(ks * 32 + row) * 4096 + hwb0 + col4 * 4;
            __builtin_amdgcn_global_load_lds(
                (const __attribute__((address_space(1))) void*)gsrc,
                (__attribute__((address_space(3))) void*)(az + (size_t)u * 16), 16, 0, 0);
        }
        __syncthreads();
#pragma unroll
        for (int m = 0; m < 2; m++) {
            half8 h;
            float ss = s1p[m];
#pragma unroll
            for (int j = 0; j < 8; j++) {
                float f = *(const float*)(az +
                        (size_t)(((l4 * 8 + j) * 128) + wave * 32 + m * 16 + l15) * 4) * 32.f;
                h[j] = (_Float16)f;
                ss = fmaf(f, f, ss);
            }
            aHi[m][ks] = h;
            s1p[m] = ss;
        }
    }
    __syncthreads();
#pragma unroll
    for (int m = 0; m < 2; m++) {
        s1p[m] += __shfl_xor(s1p[m], 16);
        s1p[m] += __shfl_xor(s1p[m], 32);
    }

    float bestv[2][4], bestv2[2][4];
    int besti[2][4];
#pragma unroll
    for (int m = 0; m < 2; m++)
#pragma unroll
        for (int j = 0; j < 4; j++) { bestv[m][j] = 3.0e38f; bestv2[m][j] = 3.0e38f; besti[m][j] = 0; }

    // barrier-free K-loop: B fragments straight from L2-resident image
    const unsigned char* ib = img + (size_t)lane * 16;
    for (int chunk = 0; chunk < 32; chunk++) {
        const unsigned char* cb8 = ib + (size_t)chunk * 16384;
        f32x4 acc[2][2];
#pragma unroll
        for (int m = 0; m < 2; m++)
#pragma unroll
            for (int q = 0; q < 2; q++) acc[m][q] = (f32x4){0.f, 0.f, 0.f, 0.f};
#pragma unroll
        for (int ks = 0; ks < 8; ks++) {
            half8 b0 = *(const half8*)(cb8 + (ks << 11));
            half8 b1 = *(const half8*)(cb8 + (ks << 11) + 1024);
#pragma unroll
            for (int m = 0; m < 2; m++) {
                acc[m][0] = __builtin_amdgcn_mfma_f32_16x16x32_f16(aHi[m][ks], b0, acc[m][0], 0, 0, 0);
                acc[m][1] = __builtin_amdgcn_mfma_f32_16x16x32_f16(aHi[m][ks], b1, acc[m][1], 0, 0, 0);
            }
        }
#pragma unroll
        for (int q = 0; q < 2; q++) {
            int code = chunk * 32 + q * 16 + l15;
            float ev = e2s[code];
#pragma unroll
            for (int m = 0; m < 2; m++)
#pragma unroll
                for (int j = 0; j < 4; j++) {
                    float s = fmaf(acc[m][q][j], -6.103515625e-05f, ev);
                    if (s < bestv[m][j]) { bestv2[m][j] = bestv[m][j]; bestv[m][j] = s; besti[m][j] = code; }
                    else if (s < bestv2[m][j]) bestv2[m][j] = s;
                }
        }
    }

    float lsum = 0.f;
#pragma unroll
    for (int m = 0; m < 2; m++)
#pragma unroll
        for (int j = 0; j < 4; j++) {
            float v = bestv[m][j], v2 = bestv2[m][j];
            int idx = besti[m][j];
#pragma unroll
            for (int off = 1; off < 16; off <<= 1) {
                float ov = __shfl_xor(v, off);
                float ov2 = __shfl_xor(v2, off);
                int oi = __shfl_xor(idx, off);
                if (ov < v || (ov == v && oi < idx)) { v2 = fminf(v, ov2); v = ov; idx = oi; }
                else v2 = fminf(v2, ov);
            }
            int r = l4 * 4 + j;
            float S1r = __shfl(s1p[m], r) * 9.765625e-4f;   // /1024 (f = 32z)
            if (l15 == 0) {
                lsum += S1r + v;
                int p = wbase + m * 16 + l4 * 4 + j;
                outIdx[p] = idx;
                if (v2 - v < MARGIN) {
                    int pos = atomicAdd(cnt, 1);
                    if (pos < CAP) list[pos] = p;
                }
            }
        }
#pragma unroll
    for (int off = 32; off > 0; off >>= 1) lsum += __shfl_down(lsum, off);
    if (lane == 0) lred[wave] = lsum;
    __syncthreads();
    if (t == 0) partial[blockIdx.x] = lred[0] + lred[1] + lred[2] + lred[3];
}

// ---------------- cbT after vq_dist (aliases dead img region; 1MB fits before WS_S2) ------
__global__ __launch_bounds__(256) void vq_cbt(const float* __restrict__ cb,
                                              float* __restrict__ cbT) {
    int k = blockIdx.x * 256 + threadIdx.x;
    for (int c = 0; c < 256; c++) cbT[c * 1024 + k] = cb[(size_t)k * 256 + c];
}

__global__ __launch_bounds__(256) void vq_rescue(const float* __restrict__ z,
                                                 const float* __restrict__ cbT,
                                                 const float* __restrict__ s2,
                                                 const int* __restrict__ list,
                                                 const int* __restrict__ cnt,
                                                 int* __restrict__ outIdx) {
    __shared__ float zs[8][256];
    __shared__ float S1s[8];
    __shared__ float rv[256];
    __shared__ int ri[256];
    int n = *cnt; if (n > CAP) n = CAP;
    int t = threadIdx.x;
    for (int base = blockIdx.x * 8; base < n; base += gridDim.x * 8) {
        int npts = n - base; if (npts > 8) npts = 8;
        __syncthreads();
        {
            int pp = t >> 5, c0 = (t & 31) * 8;
            if (pp < npts) {
                int p = list[base + pp];
                int b = p >> 12, hw = p & 4095;
                const float* zp = z + ((size_t)b << 20) + hw;
#pragma unroll
                for (int j = 0; j < 8; j++) zs[pp][c0 + j] = zp[(size_t)(c0 + j) << 12];
            }
        }
        __syncthreads();
        if (t < npts) S1s[t] = np_pairwise_sq_256(zs[t]);
        __syncthreads();

        float d[8][4];
#pragma unroll
        for (int pp = 0; pp < 8; pp++)
#pragma unroll
            for (int q = 0; q < 4; q++) d[pp][q] = 0.f;
        for (int c = 0; c < 256; c++) {
            const float* er = cbT + c * 1024 + t;
            float e0 = er[0], e1 = er[256], e2v = er[512], e3 = er[768];
#pragma unroll
            for (int pp = 0; pp < 8; pp++) {
                float zc = zs[pp][c];
                d[pp][0] = fmaf(zc, e0, d[pp][0]);
                d[pp][1] = fmaf(zc, e1, d[pp][1]);
                d[pp][2] = fmaf(zc, e2v, d[pp][2]);
                d[pp][3] = fmaf(zc, e3, d[pp][3]);
            }
        }
        float s2v[4] = {s2[t], s2[256 + t], s2[512 + t], s2[768 + t]};

        float bv[8]; int bi[8];
#pragma unroll
        for (int pp = 0; pp < 8; pp++) {
            float v = 3.4e38f; int i0 = 0;
#pragma unroll
            for (int q = 0; q < 4; q++) {
                float dist = __fsub_rn(__fadd_rn(S1s[pp], s2v[q]), __fmul_rn(2.0f, d[pp][q]));
                if (dist < v) { v = dist; i0 = q * 256 + t; }
            }
            bv[pp] = v; bi[pp] = i0;
        }
        for (int pp = 0; pp < 8; pp++) {
            if (pp >= npts) break;
            rv[t] = bv[pp]; ri[t] = bi[pp];
            __syncthreads();
            for (int sft = 128; sft > 0; sft >>= 1) {
                if (t < sft) {
                    if (rv[t + sft] < rv[t] || (rv[t + sft] == rv[t] && ri[t + sft] < ri[t])) {
                        rv[t] = rv[t + sft]; ri[t] = ri[t + sft];
                    }
                }
                __syncthreads();
            }
            if (t == 0) outIdx[list[base + pp]] = ri[0];
            __syncthreads();
        }
    }
}

// ---------------- gather v3: write-only (z_q from codebook + indices) ----------
__global__ __launch_bounds__(256) void vq_gather(const float* __restrict__ cb,
                                                 const int* __restrict__ idxs,
                                                 float* __restrict__ out) {
    int unit = blockIdx.x * 256 + threadIdx.x;
    int hw4 = unit & 1023;
    int cgb = unit >> 10;
    int b = cgb >> 5, cg = cgb & 31;

    int4 ids = *(const int4*)&idxs[(b << 12) + hw4 * 4];
    float va[4][8];
#pragma unroll
    for (int e = 0; e < 4; e++) {
        int id = (e == 0) ? ids.x : (e == 1) ? ids.y : (e == 2) ? ids.z : ids.w;
        const float4* cr = (const float4*)(cb + (size_t)id * CDIM + cg * 8);
        float4 v0 = cr[0], v1 = cr[1];
        va[e][0] = v0.x; va[e][1] = v0.y; va[e][2] = v0.z; va[e][3] = v0.w;
        va[e][4] = v1.x; va[e][5] = v1.y; va[e][6] = v1.z; va[e][7] = v1.w;
    }
#pragma unroll
    for (int j = 0; j < 8; j++) {
        size_t addr = (((size_t)(b * 256 + cg * 8 + j)) << 12) + hw4 * 4;
        float4 ov = {va[0][j], va[1][j], va[2][j], va[3][j]};
        *(float4*)&out[addr] = ov;
    }
    if (cg == 0) {
        size_t ib = (size_t)ZQ_ELEMS + 1u + (b << 12) + hw4 * 4;
        out[ib + 0] = (float)ids.x;
        out[ib + 1] = (float)ids.y;
        out[ib + 2] = (float)ids.z;
        out[ib + 3] = (float)ids.w;
    }
}

__global__ __launch_bounds__(1024) void vq_finalize(const float* __restrict__ partial,
                                                    float* __restrict__ out) {
    int t = threadIdx.x;
    double s = (double)partial[t];
#pragma unroll
    for (int off = 32; off > 0; off >>= 1) s += __shfl_down(s, off);
    __shared__ double sd[16];
    if ((t & 63) == 0) sd[t >> 6] = s;
    __syncthreads();
    if (t == 0) {
        double tot = 0.0;
        for (int i = 0; i < 16; i++) tot += sd[i];
        out[ZQ_ELEMS] = (float)(1.25 * tot / (double)ZQ_ELEMS);
    }
}

extern "C" void kernel_launch(void* const* d_in, const int* in_sizes, int n_in,
                              void* d_out, int out_size, void* d_ws, size_t ws_size,
                              hipStream_t stream) {
    const float* z = (const float*)d_in[0];
    const float* cb = (const float*)d_in[1];
    unsigned char* ws = (unsigned char*)d_ws;
    unsigned char* img = ws + WS_IMG;
    float* cbT = (float*)(ws + WS_IMG);          // aliases img region (dead after vq_dist)
    float* s2 = (float*)(ws + WS_S2);
    int* idx = (int*)(ws + WS_IDX);
    float* partial = (float*)(ws + WS_PART);
    int* cnt = (int*)(ws + WS_CNT);
    int* list = (int*)(ws + WS_LIST);
    float* out = (float*)d_out;

    vq_prepall<<<32, 256, 0, stream>>>(cb, img, s2, cnt);
    vq_dist<<<1024, 256, 0, stream>>>(z, img, s2, idx, cnt, list, partial);
    vq_cbt<<<4, 256, 0, stream>>>(cb, cbT);
    vq_rescue<<<512, 256, 0, stream>>>(z, cbT, s2, list, cnt, idx);
    vq_gather<<<4096, 256, 0, stream>>>(cb, idx, out);
    vq_finalize<<<1, 1024, 0, stream>>>(partial, out);
}

// Round 23
// 318.966 us; speedup vs baseline: 1.1004x; 1.1004x over previous
//
#include <hip/hip_runtime.h>
#include <stdint.h>

typedef __attribute__((ext_vector_type(8))) _Float16 half8;
typedef __attribute__((ext_vector_type(4))) float f32x4;

#define CDIM 256
#define KCODES 1024
#define NPTS 131072
#define ZQ_ELEMS 33554432u
#define CAP 32768
#define MARGIN 3.0e-4f

// ws layout (bytes). cbT (1MB) lives in d_out's z_q region: written by prepall,
// read by rescue, overwritten by gather (strictly ordered on the stream).
#define WS_IMG 0
#define WS_S2 (16 * 65536)
#define WS_IDX (WS_S2 + 4096)
#define WS_PART (WS_IDX + NPTS * 4)
#define WS_CNT (WS_PART + 65536)
#define WS_LIST (WS_CNT + 64)

__device__ __forceinline__ float np_pairwise_sq_256(const float* x) {
    float res[2];
#pragma unroll
    for (int h = 0; h < 2; h++) {
        const float* a = x + h * 128;
        float r[8];
#pragma unroll
        for (int j = 0; j < 8; j++) r[j] = __fmul_rn(a[j], a[j]);
#pragma unroll
        for (int i = 8; i < 128; i += 8)
#pragma unroll
            for (int j = 0; j < 8; j++)
                r[j] = __fadd_rn(r[j], __fmul_rn(a[i + j], a[i + j]));
        res[h] = __fadd_rn(__fadd_rn(__fadd_rn(r[0], r[1]), __fadd_rn(r[2], r[3])),
                           __fadd_rn(__fadd_rn(r[4], r[5]), __fadd_rn(r[6], r[7])));
    }
    return __fadd_rn(res[0], res[1]);
}

// ---------------- fused prep: img fragments + s2 + cbT (32 codes/block, 32 blocks) --------
__global__ __launch_bounds__(256) void vq_prepall(const float* __restrict__ cb,
                                                  unsigned char* __restrict__ img,
                                                  float* __restrict__ s2,
                                                  float* __restrict__ cbT,
                                                  int* __restrict__ cnt) {
    __shared__ float rows[32 * 261];
    int t = threadIdx.x;
    int k0 = blockIdx.x * 32;
    if (blockIdx.x == 0 && t == 0) *cnt = 0;
#pragma unroll
    for (int i = 0; i < 8; i++) {
        int u = i * 256 + t;
        int row = u >> 6, c4 = u & 63;
        float4 v = *(const float4*)&cb[(size_t)(k0 + row) * CDIM + c4 * 4];
        float* d = &rows[row * 261 + c4 * 4];
        d[0] = v.x; d[1] = v.y; d[2] = v.z; d[3] = v.w;
    }
    __syncthreads();
    if (t < 32) s2[k0 + t] = np_pairwise_sq_256(&rows[t * 261]);
    // img fragments (r13 layout): chunk=blockIdx, slot = ks*2+q, lane*16 within
#pragma unroll
    for (int i = 0; i < 4; i++) {
        int u = i * 256 + t;
        int cl = u >> 5, cg = u & 31;
        union H { _Float16 h[8]; uint4 u4; } hv;
#pragma unroll
        for (int j = 0; j < 8; j++) hv.h[j] = (_Float16)(rows[cl * 261 + cg * 8 + j] * 1024.f);
        int ks = cg >> 2, l4 = cg & 3;
        int q = cl >> 4, l15 = cl & 15;
        int lane = l4 * 16 + l15;
        *(uint4*)(img + (size_t)blockIdx.x * 16384 + ((ks * 2 + q) << 10) + lane * 16) = hv.u4;
    }
    // cbT[c][k0+row] (to d_out scratch; coalesced in k)
#pragma unroll
    for (int i = 0; i < 32; i++) {
        int u = i * 256 + t;
        int c = u >> 5, row = u & 31;
        cbT[(size_t)c * 1024 + k0 + row] = rows[row * 261 + c];
    }
}

// ---------------- pass 1 (r20, verified passing; byte-identical) ----------------
__global__ __launch_bounds__(256, 2) void vq_dist(const float* __restrict__ z,
                                                  const unsigned char* __restrict__ img,
                                                  const float* __restrict__ s2g,
                                                  int* __restrict__ outIdx,
                                                  int* __restrict__ cnt,
                                                  int* __restrict__ list,
                                                  float* __restrict__ partial) {
    __shared__ __align__(16) unsigned char smem[3][16384];
    __shared__ float e2s[1024];
    __shared__ float lred[4];
    int t = threadIdx.x;
    int lane = t & 63, wave = t >> 6;
    int l15 = lane & 15, l4 = lane >> 4;
    int blk0 = blockIdx.x * 256;
    int wbase = blk0 + wave * 64;
    int b = blk0 >> 12;
    int hwb0 = blk0 & 4095;
    const float* zb = z + (size_t)b * (CDIM * 4096);
    unsigned char* sbase = &smem[0][0];

#pragma unroll
    for (int i = 0; i < 4; i++) e2s[t + i * 256] = s2g[t + i * 256];

    half8 aHi[4][8];
    float s1p[4] = {0.f, 0.f, 0.f, 0.f};
#pragma unroll
    for (int ks = 0; ks < 8; ks++) {
        __syncthreads();
#pragma unroll
        for (int i = 0; i < 8; i++) {
            int u = i * 256 + t;
            int row = u >> 6, col16 = u & 63;
            const float* gsrc = zb + (size_t)(ks * 32 + row) * 4096 + hwb0 + col16 * 4;
            __builtin_amdgcn_global_load_lds(
                (const __attribute__((address_space(1))) void*)gsrc,
                (__attribute__((address_space(3))) void*)(sbase + (size_t)u * 16), 16, 0, 0);
        }
        __syncthreads();
#pragma unroll
        for (int m = 0; m < 4; m++) {
            half8 h;
            float ss = s1p[m];
#pragma unroll
            for (int j = 0; j < 8; j++) {
                float f = *(const float*)(sbase +
                        (size_t)(((l4 * 8 + j) << 8) + wave * 64 + m * 16 + l15) * 4) * 32.f;
                h[j] = (_Float16)f;
                ss = fmaf(f, f, ss);
            }
            aHi[m][ks] = h;
            s1p[m] = ss;
        }
    }
    __syncthreads();
#pragma unroll
    for (int m = 0; m < 4; m++) {
        s1p[m] += __shfl_xor(s1p[m], 16);
        s1p[m] += __shfl_xor(s1p[m], 32);
    }

#pragma unroll
    for (int i = 0; i < 4; i++) {
        size_t off = (size_t)(i * 256 + t) * 16;
        __builtin_amdgcn_global_load_lds(
            (const __attribute__((address_space(1))) void*)(img + off),
            (__attribute__((address_space(3))) void*)(&smem[0][0] + off), 16, 0, 0);
    }
#pragma unroll
    for (int i = 0; i < 4; i++) {
        size_t off = (size_t)(i * 256 + t) * 16;
        __builtin_amdgcn_global_load_lds(
            (const __attribute__((address_space(1))) void*)(img + 16384 + off),
            (__attribute__((address_space(3))) void*)(&smem[1][0] + off), 16, 0, 0);
    }

    float bestv[4][4], bestv2[4][4];
    int besti[4][4];
#pragma unroll
    for (int m = 0; m < 4; m++)
#pragma unroll
        for (int j = 0; j < 4; j++) { bestv[m][j] = 3.0e38f; bestv2[m][j] = 3.0e38f; besti[m][j] = 0; }

    int i0 = 0, i1 = 1, i2 = 2;
    for (int chunk = 0; chunk < 32; chunk++) {
        if (chunk < 31) asm volatile("s_waitcnt vmcnt(4)" ::: "memory");
        else            asm volatile("s_waitcnt vmcnt(0)" ::: "memory");
        __builtin_amdgcn_s_barrier();

        if (chunk + 2 < 32) {
            const unsigned char* src = img + (size_t)(chunk + 2) * 16384;
            unsigned char* dst = &smem[0][0] + (size_t)i2 * 16384;
#pragma unroll
            for (int i = 0; i < 4; i++) {
                size_t off = (size_t)(i * 256 + t) * 16;
                __builtin_amdgcn_global_load_lds(
                    (const __attribute__((address_space(1))) void*)(src + off),
                    (__attribute__((address_space(3))) void*)(dst + off), 16, 0, 0);
            }
        }

        f32x4 acc[4][2];
#pragma unroll
        for (int m = 0; m < 4; m++)
#pragma unroll
            for (int q = 0; q < 2; q++) acc[m][q] = (f32x4){0.f, 0.f, 0.f, 0.f};

        const unsigned char* bufc = &smem[0][0] + (size_t)i0 * 16384 + lane * 16;
#pragma unroll
        for (int ks = 0; ks < 8; ks++) {
            half8 b0 = *(const half8*)(bufc + (ks << 11));
            half8 b1 = *(const half8*)(bufc + (ks << 11) + 1024);
#pragma unroll
            for (int m = 0; m < 4; m++) {
                acc[m][0] = __builtin_amdgcn_mfma_f32_16x16x32_f16(aHi[m][ks], b0, acc[m][0], 0, 0, 0);
                acc[m][1] = __builtin_amdgcn_mfma_f32_16x16x32_f16(aHi[m][ks], b1, acc[m][1], 0, 0, 0);
            }
        }
#pragma unroll
        for (int q = 0; q < 2; q++) {
            int code = chunk * 32 + q * 16 + l15;
            float ev = e2s[code];
#pragma unroll
            for (int m = 0; m < 4; m++)
#pragma unroll
                for (int j = 0; j < 4; j++) {
                    float s = fmaf(acc[m][q][j], -6.103515625e-05f, ev);
                    if (s < bestv[m][j]) { bestv2[m][j] = bestv[m][j]; bestv[m][j] = s; besti[m][j] = code; }
                    else if (s < bestv2[m][j]) bestv2[m][j] = s;
                }
        }
        int tmp = i0; i0 = i1; i1 = i2; i2 = tmp;
    }

    float lsum = 0.f;
#pragma unroll
    for (int m = 0; m < 4; m++)
#pragma unroll
        for (int j = 0; j < 4; j++) {
            float v = bestv[m][j], v2 = bestv2[m][j];
            int idx = besti[m][j];
#pragma unroll
            for (int off = 1; off < 16; off <<= 1) {
                float ov = __shfl_xor(v, off);
                float ov2 = __shfl_xor(v2, off);
                int oi = __shfl_xor(idx, off);
                if (ov < v || (ov == v && oi < idx)) { v2 = fminf(v, ov2); v = ov; idx = oi; }
                else v2 = fminf(v2, ov);
            }
            int r = l4 * 4 + j;
            float S1r = __shfl(s1p[m], r) * 9.765625e-4f;   // /1024 (f = 32z)
            if (l15 == 0) {
                lsum += S1r + v;
                int p = wbase + m * 16 + l4 * 4 + j;
                outIdx[p] = idx;
                if (v2 - v < MARGIN) {
                    int pos = atomicAdd(cnt, 1);
                    if (pos < CAP) list[pos] = p;
                }
            }
        }
#pragma unroll
    for (int off = 32; off > 0; off >>= 1) lsum += __shfl_down(lsum, off);
    if (lane == 0) lred[wave] = lsum;
    __syncthreads();
    if (t == 0) partial[blockIdx.x] = lred[0] + lred[1] + lred[2] + lred[3];
}

__global__ __launch_bounds__(256) void vq_rescue(const float* __restrict__ z,
                                                 const float* __restrict__ cbT,
                                                 const float* __restrict__ s2,
                                                 const int* __restrict__ list,
                                                 const int* __restrict__ cnt,
                                                 int* __restrict__ outIdx) {
    __shared__ float zs[8][256];
    __shared__ float S1s[8];
    __shared__ float rv[256];
    __shared__ int ri[256];
    int n = *cnt; if (n > CAP) n = CAP;
    int t = threadIdx.x;
    for (int base = blockIdx.x * 8; base < n; base += gridDim.x * 8) {
        int npts = n - base; if (npts > 8) npts = 8;
        __syncthreads();
        {
            int pp = t >> 5, c0 = (t & 31) * 8;
            if (pp < npts) {
                int p = list[base + pp];
                int b = p >> 12, hw = p & 4095;
                const float* zp = z + ((size_t)b << 20) + hw;
#pragma unroll
                for (int j = 0; j < 8; j++) zs[pp][c0 + j] = zp[(size_t)(c0 + j) << 12];
            }
        }
        __syncthreads();
        if (t < npts) S1s[t] = np_pairwise_sq_256(zs[t]);
        __syncthreads();

        float d[8][4];
#pragma unroll
        for (int pp = 0; pp < 8; pp++)
#pragma unroll
            for (int q = 0; q < 4; q++) d[pp][q] = 0.f;
        for (int c = 0; c < 256; c++) {
            const float* er = cbT + c * 1024 + t;
            float e0 = er[0], e1 = er[256], e2v = er[512], e3 = er[768];
#pragma unroll
            for (int pp = 0; pp < 8; pp++) {
                float zc = zs[pp][c];
                d[pp][0] = fmaf(zc, e0, d[pp][0]);
                d[pp][1] = fmaf(zc, e1, d[pp][1]);
                d[pp][2] = fmaf(zc, e2v, d[pp][2]);
                d[pp][3] = fmaf(zc, e3, d[pp][3]);
            }
        }
        float s2v[4] = {s2[t], s2[256 + t], s2[512 + t], s2[768 + t]};

        float bv[8]; int bi[8];
#pragma unroll
        for (int pp = 0; pp < 8; pp++) {
            float v = 3.4e38f; int i0 = 0;
#pragma unroll
            for (int q = 0; q < 4; q++) {
                float dist = __fsub_rn(__fadd_rn(S1s[pp], s2v[q]), __fmul_rn(2.0f, d[pp][q]));
                if (dist < v) { v = dist; i0 = q * 256 + t; }
            }
            bv[pp] = v; bi[pp] = i0;
        }
        for (int pp = 0; pp < 8; pp++) {
            if (pp >= npts) break;
            rv[t] = bv[pp]; ri[t] = bi[pp];
            __syncthreads();
            for (int sft = 128; sft > 0; sft >>= 1) {
                if (t < sft) {
                    if (rv[t + sft] < rv[t] || (rv[t + sft] == rv[t] && ri[t + sft] < ri[t])) {
                        rv[t] = rv[t + sft]; ri[t] = ri[t + sft];
                    }
                }
                __syncthreads();
            }
            if (t == 0) outIdx[list[base + pp]] = ri[0];
            __syncthreads();
        }
    }
}

// ---------------- gather v3: write-only (z_q from codebook + indices) ----------
__global__ __launch_bounds__(256) void vq_gather(const float* __restrict__ cb,
                                                 const int* __restrict__ idxs,
                                                 float* __restrict__ out) {
    int unit = blockIdx.x * 256 + threadIdx.x;
    int hw4 = unit & 1023;
    int cgb = unit >> 10;
    int b = cgb >> 5, cg = cgb & 31;

    int4 ids = *(const int4*)&idxs[(b << 12) + hw4 * 4];
    float va[4][8];
#pragma unroll
    for (int e = 0; e < 4; e++) {
        int id = (e == 0) ? ids.x : (e == 1) ? ids.y : (e == 2) ? ids.z : ids.w;
        const float4* cr = (const float4*)(cb + (size_t)id * CDIM + cg * 8);
        float4 v0 = cr[0], v1 = cr[1];
        va[e][0] = v0.x; va[e][1] = v0.y; va[e][2] = v0.z; va[e][3] = v0.w;
        va[e][4] = v1.x; va[e][5] = v1.y; va[e][6] = v1.z; va[e][7] = v1.w;
    }
#pragma unroll
    for (int j = 0; j < 8; j++) {
        size_t addr = (((size_t)(b * 256 + cg * 8 + j)) << 12) + hw4 * 4;
        float4 ov = {va[0][j], va[1][j], va[2][j], va[3][j]};
        *(float4*)&out[addr] = ov;
    }
    if (cg == 0) {
        size_t ib = (size_t)ZQ_ELEMS + 1u + (b << 12) + hw4 * 4;
        out[ib + 0] = (float)ids.x;
        out[ib + 1] = (float)ids.y;
        out[ib + 2] = (float)ids.z;
        out[ib + 3] = (float)ids.w;
    }
}

__global__ __launch_bounds__(512) void vq_finalize(const float* __restrict__ partial,
                                                   float* __restrict__ out) {
    int t = threadIdx.x;
    double s = (double)partial[t];
#pragma unroll
    for (int off = 32; off > 0; off >>= 1) s += __shfl_down(s, off);
    __shared__ double sd[8];
    if ((t & 63) == 0) sd[t >> 6] = s;
    __syncthreads();
    if (t == 0) {
        double tot = sd[0] + sd[1] + sd[2] + sd[3] + sd[4] + sd[5] + sd[6] + sd[7];
        out[ZQ_ELEMS] = (float)(1.25 * tot / (double)ZQ_ELEMS);
    }
}

extern "C" void kernel_launch(void* const* d_in, const int* in_sizes, int n_in,
                              void* d_out, int out_size, void* d_ws, size_t ws_size,
                              hipStream_t stream) {
    const float* z = (const float*)d_in[0];
    const float* cb = (const float*)d_in[1];
    unsigned char* ws = (unsigned char*)d_ws;
    unsigned char* img = ws + WS_IMG;
    float* s2 = (float*)(ws + WS_S2);
    int* idx = (int*)(ws + WS_IDX);
    float* partial = (float*)(ws + WS_PART);
    int* cnt = (int*)(ws + WS_CNT);
    int* list = (int*)(ws + WS_LIST);
    float* out = (float*)d_out;
    // cbT (1MB) in d_out's z_q region: prepall writes -> rescue reads -> gather overwrites.
    float* cbT = (float*)d_out;

    vq_prepall<<<32, 256, 0, stream>>>(cb, img, s2, cbT, cnt);
    vq_dist<<<512, 256, 0, stream>>>(z, img, s2, idx, cnt, list, partial);
    vq_rescue<<<1024, 256, 0, stream>>>(z, cbT, s2, list, cnt, idx);
    vq_gather<<<4096, 256, 0, stream>>>(cb, idx, out);
    vq_finalize<<<1, 512, 0, stream>>>(partial, out);
}